// Round 8
// baseline (336.356 us; speedup 1.0000x reference)
//
#include <hip/hip_runtime.h>
#include <hip/hip_bf16.h>
#include <math.h>

typedef __bf16 bf16;
typedef __bf16 bf16x4 __attribute__((ext_vector_type(4)));
typedef __bf16 bf16x8 __attribute__((ext_vector_type(8)));
typedef float floatx4 __attribute__((ext_vector_type(4)));
typedef short short4v __attribute__((ext_vector_type(4)));

#define S_LEN 4096
#define DM 1024
#define NH 16
#define HD 64

#define GM 4096
#define GN 1024
#define GK 1024
#define LDST 72    // GEMM LDS row stride (64 + 8)
#define FST 68     // flash LDS row stride (zero measured conflicts, r3-r7)

__device__ __forceinline__ bf16x8 cvt8(float4 a, float4 b) {
    return (bf16x8){ (bf16)a.x, (bf16)a.y, (bf16)a.z, (bf16)a.w,
                     (bf16)b.x, (bf16)b.y, (bf16)b.z, (bf16)b.w };
}

// ---------------------------------------------------------------------------
// Fused QKV GEMM. C = x * W^T, x fp32 (4096x1024), W fp32 (1024x1024).
// fp32->bf16 conversion fused into LDS staging. Epilogue per z:
//   z=0/1 (Q/K): RoPE applied in-register (pair via shfl_xor(1)), bf16 store.
//   z=2   (V):   transposed store -> VT[d_global][s] (packed bf16x4 over rows).
// ---------------------------------------------------------------------------
__launch_bounds__(256)
__global__ void gemm_qkv(const float* __restrict__ x,
                         const float* __restrict__ wq, const float* __restrict__ wk,
                         const float* __restrict__ wv,
                         const float* __restrict__ cosp, const float* __restrict__ sinp,
                         bf16* __restrict__ Qw, bf16* __restrict__ Kw,
                         bf16* __restrict__ VTw)
{
    const int bz = blockIdx.z;
    const float* __restrict__ B = (bz == 0) ? wq : (bz == 1 ? wk : wv);

    const int tid  = threadIdx.x;
    const int wave = tid >> 6;
    const int lane = tid & 63;
    const int wm   = (wave >> 1) * 64;
    const int wn   = (wave & 1) * 64;
    const int lrow = lane >> 4;
    const int lcol = lane & 15;

    const int m0 = blockIdx.y * 128;
    const int n0 = blockIdx.x * 128;

    __shared__ __align__(16) bf16 As[128 * LDST];
    __shared__ __align__(16) bf16 Bs[128 * LDST];

    floatx4 acc[4][4];
    #pragma unroll
    for (int i = 0; i < 4; i++)
        #pragma unroll
        for (int j = 0; j < 4; j++) acc[i][j] = (floatx4){0.f, 0.f, 0.f, 0.f};

    for (int kt = 0; kt < GK; kt += 64) {
        #pragma unroll
        for (int i = 0; i < 4; i++) {
            int idx = i * 256 + tid;
            int row = idx >> 3;
            int ch  = (idx & 7) * 8;
            const float* ap = &x[(size_t)(m0 + row) * GK + kt + ch];
            const float* bp = &B[(size_t)(n0 + row) * GK + kt + ch];
            float4 a0 = *(const float4*)(ap), a1 = *(const float4*)(ap + 4);
            float4 b0 = *(const float4*)(bp), b1 = *(const float4*)(bp + 4);
            *(bf16x8*)(&As[row * LDST + ch]) = cvt8(a0, a1);
            *(bf16x8*)(&Bs[row * LDST + ch]) = cvt8(b0, b1);
        }
        __syncthreads();
        #pragma unroll
        for (int ks = 0; ks < 2; ks++) {
            bf16x8 af[4], bfr[4];
            #pragma unroll
            for (int t = 0; t < 4; t++) {
                af[t]  = *(const bf16x8*)(&As[(wm + t * 16 + lcol) * LDST + ks * 32 + lrow * 8]);
                bfr[t] = *(const bf16x8*)(&Bs[(wn + t * 16 + lcol) * LDST + ks * 32 + lrow * 8]);
            }
            #pragma unroll
            for (int mt = 0; mt < 4; mt++)
                #pragma unroll
                for (int nt = 0; nt < 4; nt++)
                    acc[mt][nt] = __builtin_amdgcn_mfma_f32_16x16x32_bf16(af[mt], bfr[nt], acc[mt][nt], 0, 0, 0);
        }
        __syncthreads();
    }

    if (bz < 2) {
        // Q/K with fused RoPE. col = n0+wn+nt*16+lcol; within-head d' = nt*16+lcol
        // (n0,wn are multiples of 64). Pair partner is lane lcol^1, same row.
        bf16* __restrict__ C = bz ? Kw : Qw;
        const bool odd = (lcol & 1);
        #pragma unroll
        for (int mt = 0; mt < 4; mt++)
            #pragma unroll
            for (int nt = 0; nt < 4; nt++) {
                int i = (nt * 16 + lcol) >> 1;   // freq index 0..31
                #pragma unroll
                for (int r = 0; r < 4; r++) {
                    float v  = acc[mt][nt][r];
                    float pv = __shfl_xor(v, 1, 64);
                    int s = m0 + wm + mt * 16 + lrow * 4 + r;
                    float c  = cosp[s * 32 + i];
                    float sn = sinp[s * 32 + i];
                    // even d': out = e*c - o*sn ; odd d': out = e*sn + o*c
                    float ov = odd ? (pv * sn + v * c) : (v * c - pv * sn);
                    C[(size_t)s * GN + n0 + wn + nt * 16 + lcol] = (bf16)ov;
                }
            }
    } else {
        // V: store transposed. VT[col][s], rows r contiguous -> packed bf16x4.
        #pragma unroll
        for (int mt = 0; mt < 4; mt++)
            #pragma unroll
            for (int nt = 0; nt < 4; nt++) {
                int col = n0 + wn + nt * 16 + lcol;
                int s   = m0 + wm + mt * 16 + lrow * 4;
                bf16x4 ov = { (bf16)acc[mt][nt][0], (bf16)acc[mt][nt][1],
                              (bf16)acc[mt][nt][2], (bf16)acc[mt][nt][3] };
                *(bf16x4*)(&VTw[(size_t)col * S_LEN + s]) = ov;
            }
    }
}

// ---------------------------------------------------------------------------
// Flash attention v5 (unchanged from r7): parity-split + shared-K dual-q.
// Grid (64, NH). Block (pair pi=bx>>1, parity p=bx&1) does k-tiles t≡p (mod 2)
// for both q-tiles {pi, 63-pi}. Unnormalized fp32 partials + l per parity.
// ---------------------------------------------------------------------------
__launch_bounds__(256, 4)
__global__ void flash_attn(const bf16* __restrict__ Q, const bf16* __restrict__ K,
                           const bf16* __restrict__ VT,
                           float* __restrict__ O0, float* __restrict__ O1,
                           float* __restrict__ L0, float* __restrict__ L1)
{
    const int pi   = blockIdx.x >> 1;
    const int p    = blockIdx.x & 1;
    const int h    = blockIdx.y;
    const int tid  = threadIdx.x;
    const int wave = tid >> 6;
    const int lane = tid & 63;
    const int lrow = lane >> 4;
    const int lcol = lane & 15;

    const int qtA = pi;
    const int qtB = 63 - pi;

    float* __restrict__ Op = p ? O1 : O0;
    float* __restrict__ Lp = p ? L1 : L0;

    __shared__ __align__(16) bf16 Ks[2][64 * FST];
    __shared__ __align__(16) bf16 Vs[2][64 * FST];

    const float sc2 = 0.125f * 1.44269504088896340736f;

    const int q0A = qtA * 64 + wave * 16;
    const int q0B = qtB * 64 + wave * 16;

    const bf16* qpA = Q + (size_t)(q0A + lcol) * DM + h * HD;
    const bf16* qpB = Q + (size_t)(q0B + lcol) * DM + h * HD;
    bf16x8 qfA[2], qfB[2];
    qfA[0] = *(const bf16x8*)(qpA + 0 + lrow * 8);
    qfA[1] = *(const bf16x8*)(qpA + 32 + lrow * 8);
    qfB[0] = *(const bf16x8*)(qpB + 0 + lrow * 8);
    qfB[1] = *(const bf16x8*)(qpB + 32 + lrow * 8);

    float lA = 0.f, lB = 0.f;
    floatx4 oaccA[4], oaccB[4];
    #pragma unroll
    for (int nt = 0; nt < 4; nt++) {
        oaccA[nt] = (floatx4){0.f, 0.f, 0.f, 0.f};
        oaccB[nt] = (floatx4){0.f, 0.f, 0.f, 0.f};
    }

    const int  srow = tid >> 3;
    const int  sch  = (tid & 7) * 8;
    const bf16* kp  = K  + (size_t)srow * DM + h * HD + sch;
    const bf16* vp  = VT + (size_t)(h * HD + srow) * S_LEN + sch;
    const int  wof  = srow * FST + sch;

    {
        size_t ko = (size_t)p * 64 * DM;
        size_t vo = (size_t)p * 64;
        uint4 a = *(const uint4*)(kp + ko);
        uint4 b = *(const uint4*)(kp + ko + (size_t)32 * DM);
        uint4 c = *(const uint4*)(vp + vo);
        uint4 d = *(const uint4*)(vp + vo + (size_t)32 * S_LEN);
        *(uint4*)(&Ks[0][wof])            = a;
        *(uint4*)(&Ks[0][wof + 32 * FST]) = b;
        *(uint4*)(&Vs[0][wof])            = c;
        *(uint4*)(&Vs[0][wof + 32 * FST]) = d;
    }
    __syncthreads();

    uint4 kr0, kr1, vr0, vr1;
    for (int t = p; t <= qtB; t += 2) {
        const int  cur  = ((t - p) >> 1) & 1;
        const bool more = (t + 2 <= qtB);
        const bool actA = (t <= qtA);

        if (more) {
            size_t ko = (size_t)(t + 2) * 64 * DM;
            size_t vo = (size_t)(t + 2) * 64;
            kr0 = *(const uint4*)(kp + ko);
            kr1 = *(const uint4*)(kp + ko + (size_t)32 * DM);
            vr0 = *(const uint4*)(vp + vo);
            vr1 = *(const uint4*)(vp + vo + (size_t)32 * S_LEN);
        }

        short4v pbA[4], pbB[4];
        const bool diagA = (t == qtA);
        const bool diagB = (t == qtB);
        #pragma unroll
        for (int nt = 0; nt < 4; nt++) {
            floatx4 zB = (floatx4){0.f, 0.f, 0.f, 0.f};
            floatx4 zA = (floatx4){0.f, 0.f, 0.f, 0.f};
            #pragma unroll
            for (int ks = 0; ks < 2; ks++) {
                bf16x8 kf = *(const bf16x8*)(&Ks[cur][(nt * 16 + lcol) * FST + ks * 32 + lrow * 8]);
                zB = __builtin_amdgcn_mfma_f32_16x16x32_bf16(kf, qfB[ks], zB, 0, 0, 0);
                if (actA)
                    zA = __builtin_amdgcn_mfma_f32_16x16x32_bf16(kf, qfA[ks], zA, 0, 0, 0);
            }
            if (diagB) {
                #pragma unroll
                for (int r = 0; r < 4; r++) {
                    int kg = t * 64 + nt * 16 + lrow * 4 + r;
                    float pr = exp2f(zB[r] * sc2);
                    if (kg > q0B + lcol) pr = 0.f;
                    zB[r] = pr; lB += pr;
                }
            } else {
                #pragma unroll
                for (int r = 0; r < 4; r++) {
                    float pr = exp2f(zB[r] * sc2);
                    zB[r] = pr; lB += pr;
                }
            }
            bf16x4 pvB = { (bf16)zB[0], (bf16)zB[1], (bf16)zB[2], (bf16)zB[3] };
            pbB[nt] = __builtin_bit_cast(short4v, pvB);
            if (actA) {
                if (diagA) {
                    #pragma unroll
                    for (int r = 0; r < 4; r++) {
                        int kg = t * 64 + nt * 16 + lrow * 4 + r;
                        float pr = exp2f(zA[r] * sc2);
                        if (kg > q0A + lcol) pr = 0.f;
                        zA[r] = pr; lA += pr;
                    }
                } else {
                    #pragma unroll
                    for (int r = 0; r < 4; r++) {
                        float pr = exp2f(zA[r] * sc2);
                        zA[r] = pr; lA += pr;
                    }
                }
                bf16x4 pvA = { (bf16)zA[0], (bf16)zA[1], (bf16)zA[2], (bf16)zA[3] };
                pbA[nt] = __builtin_bit_cast(short4v, pvA);
            }
        }

        #pragma unroll
        for (int nt = 0; nt < 4; nt++)
            #pragma unroll
            for (int kt = 0; kt < 4; kt++) {
                bf16x4 va = *(const bf16x4*)(&Vs[cur][(nt * 16 + lcol) * FST + kt * 16 + lrow * 4]);
                short4v vas = __builtin_bit_cast(short4v, va);
                oaccB[nt] = __builtin_amdgcn_mfma_f32_16x16x16bf16_1k(vas, pbB[kt], oaccB[nt], 0, 0, 0);
                if (actA)
                    oaccA[nt] = __builtin_amdgcn_mfma_f32_16x16x16bf16_1k(vas, pbA[kt], oaccA[nt], 0, 0, 0);
            }

        if (more) {
            int nxt = cur ^ 1;
            *(uint4*)(&Ks[nxt][wof])            = kr0;
            *(uint4*)(&Ks[nxt][wof + 32 * FST]) = kr1;
            *(uint4*)(&Vs[nxt][wof])            = vr0;
            *(uint4*)(&Vs[nxt][wof + 32 * FST]) = vr1;
        }
        __syncthreads();
    }

    lA += __shfl_xor(lA, 16, 64);
    lA += __shfl_xor(lA, 32, 64);
    lB += __shfl_xor(lB, 16, 64);
    lB += __shfl_xor(lB, 32, 64);
    if (lrow == 0) {
        Lp[h * S_LEN + q0A + lcol] = lA;
        Lp[h * S_LEN + q0B + lcol] = lB;
    }
    #pragma unroll
    for (int nt = 0; nt < 4; nt++) {
        *(floatx4*)(&Op[(size_t)(q0A + lcol) * DM + h * HD + nt * 16 + lrow * 4]) = oaccA[nt];
        *(floatx4*)(&Op[(size_t)(q0B + lcol) * DM + h * HD + nt * 16 + lrow * 4]) = oaccB[nt];
    }
}

// ---------------------------------------------------------------------------
// Fused output projection. A = (O0+O1)/(l0+l1) computed during staging
// (combine fused), B = wo (fp32->bf16 in staging), C = out fp32.
// ---------------------------------------------------------------------------
__launch_bounds__(256)
__global__ void gemm_out(const float* __restrict__ O0, const float* __restrict__ O1,
                         const float* __restrict__ L0, const float* __restrict__ L1,
                         const float* __restrict__ wo, float* __restrict__ out)
{
    const int tid  = threadIdx.x;
    const int wave = tid >> 6;
    const int lane = tid & 63;
    const int wm   = (wave >> 1) * 64;
    const int wn   = (wave & 1) * 64;
    const int lrow = lane >> 4;
    const int lcol = lane & 15;

    const int m0 = blockIdx.y * 128;
    const int n0 = blockIdx.x * 128;

    __shared__ __align__(16) bf16 As[128 * LDST];
    __shared__ __align__(16) bf16 Bs[128 * LDST];

    floatx4 acc[4][4];
    #pragma unroll
    for (int i = 0; i < 4; i++)
        #pragma unroll
        for (int j = 0; j < 4; j++) acc[i][j] = (floatx4){0.f, 0.f, 0.f, 0.f};

    for (int kt = 0; kt < GK; kt += 64) {
        #pragma unroll
        for (int i = 0; i < 4; i++) {
            int idx = i * 256 + tid;
            int row = idx >> 3;
            int ch  = (idx & 7) * 8;
            int s   = m0 + row;
            int hh  = (kt + ch) >> 6;                       // head of this chunk
            float rl = 1.f / (L0[hh * S_LEN + s] + L1[hh * S_LEN + s]);
            const float* a0p = &O0[(size_t)s * GK + kt + ch];
            const float* a1p = &O1[(size_t)s * GK + kt + ch];
            float4 a0 = *(const float4*)(a0p), a1 = *(const float4*)(a0p + 4);
            float4 b0 = *(const float4*)(a1p), b1 = *(const float4*)(a1p + 4);
            bf16x8 av = { (bf16)((a0.x + b0.x) * rl), (bf16)((a0.y + b0.y) * rl),
                          (bf16)((a0.z + b0.z) * rl), (bf16)((a0.w + b0.w) * rl),
                          (bf16)((a1.x + b1.x) * rl), (bf16)((a1.y + b1.y) * rl),
                          (bf16)((a1.z + b1.z) * rl), (bf16)((a1.w + b1.w) * rl) };
            *(bf16x8*)(&As[row * LDST + ch]) = av;
            const float* bp = &wo[(size_t)(n0 + row) * GK + kt + ch];
            float4 w0 = *(const float4*)(bp), w1 = *(const float4*)(bp + 4);
            *(bf16x8*)(&Bs[row * LDST + ch]) = cvt8(w0, w1);
        }
        __syncthreads();
        #pragma unroll
        for (int ks = 0; ks < 2; ks++) {
            bf16x8 af[4], bfr[4];
            #pragma unroll
            for (int t = 0; t < 4; t++) {
                af[t]  = *(const bf16x8*)(&As[(wm + t * 16 + lcol) * LDST + ks * 32 + lrow * 8]);
                bfr[t] = *(const bf16x8*)(&Bs[(wn + t * 16 + lcol) * LDST + ks * 32 + lrow * 8]);
            }
            #pragma unroll
            for (int mt = 0; mt < 4; mt++)
                #pragma unroll
                for (int nt = 0; nt < 4; nt++)
                    acc[mt][nt] = __builtin_amdgcn_mfma_f32_16x16x32_bf16(af[mt], bfr[nt], acc[mt][nt], 0, 0, 0);
        }
        __syncthreads();
    }

    #pragma unroll
    for (int mt = 0; mt < 4; mt++)
        #pragma unroll
        for (int nt = 0; nt < 4; nt++)
            #pragma unroll
            for (int r = 0; r < 4; r++) {
                int row = m0 + wm + mt * 16 + lrow * 4 + r;
                int col = n0 + wn + nt * 16 + lcol;
                out[(size_t)row * GN + col] = acc[mt][nt][r];
            }
}

// ---------------------------------------------------------------------------
extern "C" void kernel_launch(void* const* d_in, const int* in_sizes, int n_in,
                              void* d_out, int out_size, void* d_ws, size_t ws_size,
                              hipStream_t stream) {
    const float* x    = (const float*)d_in[0];
    const float* cosp = (const float*)d_in[1];
    const float* sinp = (const float*)d_in[2];
    const float* wq   = (const float*)d_in[4];
    const float* wk   = (const float*)d_in[5];
    const float* wv   = (const float*)d_in[6];
    const float* wo   = (const float*)d_in[7];
    float* out = (float*)d_out;

    const size_t SD = (size_t)S_LEN * DM;   // 4M elems
    bf16* Qw  = (bf16*)d_ws;                // 4M bf16 each
    bf16* Kw  = Qw + SD;
    bf16* VTw = Kw + SD;
    float* O0f = (float*)(VTw + SD);        // 4M fp32 each
    float* O1f = O0f + SD;
    float* L0f = O1f + SD;                  // 64K fp32 each
    float* L1f = L0f + (size_t)S_LEN * NH;

    // 1) QKV projections + fp32->bf16 + RoPE + V-transpose, all fused
    gemm_qkv<<<dim3(GN / 128, GM / 128, 3), 256, 0, stream>>>(
        x, wq, wk, wv, cosp, sinp, Qw, Kw, VTw);
    // 2) flash attention (parity-split partials)
    flash_attn<<<dim3(64, NH), 256, 0, stream>>>(Qw, Kw, VTw, O0f, O1f, L0f, L1f);
    // 3) output projection + combine fused
    gemm_out<<<dim3(GN / 128, GM / 128, 1), 256, 0, stream>>>(
        O0f, O1f, L0f, L1f, wo, out);
}

// Round 9
// 315.266 us; speedup vs baseline: 1.0669x; 1.0669x over previous
//
#include <hip/hip_runtime.h>
#include <hip/hip_bf16.h>
#include <math.h>

typedef __bf16 bf16;
typedef __bf16 bf16x4 __attribute__((ext_vector_type(4)));
typedef __bf16 bf16x8 __attribute__((ext_vector_type(8)));
typedef float floatx4 __attribute__((ext_vector_type(4)));
typedef short short4v __attribute__((ext_vector_type(4)));

#define S_LEN 4096
#define DM 1024
#define NH 16
#define HD 64

#define GM 4096
#define GN 1024
#define GK 1024
#define LDST 72    // padded LDS row stride (manual staging path)
#define FST 68     // flash LDS row stride (zero measured conflicts, r3-r7)

// async global->LDS, 16B per lane; lds base wave-uniform (m97/m104)
#define GLDS16(gp, lp) __builtin_amdgcn_global_load_lds( \
    (const __attribute__((address_space(1))) void*)(gp), \
    (__attribute__((address_space(3))) void*)(lp), 16, 0, 0)

__device__ __forceinline__ bf16x8 cvt8(float4 a, float4 b) {
    return (bf16x8){ (bf16)a.x, (bf16)a.y, (bf16)a.z, (bf16)a.w,
                     (bf16)b.x, (bf16)b.y, (bf16)b.z, (bf16)b.w };
}

// ---------------------------------------------------------------------------
// fp32 -> bf16: x (4M) + wq/wk/wv/wo (1M each) into contiguous ws.
// ---------------------------------------------------------------------------
__global__ void cvt_bf16(const float* __restrict__ x,  const float* __restrict__ wq,
                         const float* __restrict__ wk, const float* __restrict__ wv,
                         const float* __restrict__ wo, bf16* __restrict__ dst)
{
    size_t i4 = ((size_t)blockIdx.x * 256 + threadIdx.x) * 4;   // 8M elems total
    const float* src; size_t off;
    const size_t M1 = (size_t)1 << 20;
    if      (i4 < 4 * M1) { src = x;  off = i4;          }
    else if (i4 < 5 * M1) { src = wq; off = i4 - 4 * M1; }
    else if (i4 < 6 * M1) { src = wk; off = i4 - 5 * M1; }
    else if (i4 < 7 * M1) { src = wv; off = i4 - 6 * M1; }
    else                  { src = wo; off = i4 - 7 * M1; }
    float4 v = *(const float4*)(src + off);
    bf16x4 o = { (bf16)v.x, (bf16)v.y, (bf16)v.z, (bf16)v.w };
    *(bf16x4*)(&dst[i4]) = o;
}

// ---------------------------------------------------------------------------
// Fused QKV GEMM (bf16 in, GLDS16 staging). C = x*W^T. Epilogue per z:
//   z=0/1 (Q/K): RoPE in-register (pair via shfl_xor(1)) -> Qw/Kw bf16.
//   z=2   (V):   transposed store -> VTw[d_global][s] (packed bf16x4).
// Epilogue correctness verified end-to-end in r8 (passed, absmax 0.0156).
// ---------------------------------------------------------------------------
__launch_bounds__(256)
__global__ void gemm_qkv(const bf16* __restrict__ A,
                         const bf16* __restrict__ B0, const bf16* __restrict__ B1,
                         const bf16* __restrict__ B2,
                         const float* __restrict__ cosp, const float* __restrict__ sinp,
                         bf16* __restrict__ Qw, bf16* __restrict__ Kw,
                         bf16* __restrict__ VTw)
{
    const int bz = blockIdx.z;
    const bf16* __restrict__ B = (bz == 0) ? B0 : (bz == 1 ? B1 : B2);

    const int tid  = threadIdx.x;
    const int wave = tid >> 6;
    const int lane = tid & 63;
    const int wm   = (wave >> 1) * 64;
    const int wn   = (wave & 1) * 64;
    const int lrow = lane >> 4;
    const int lcol = lane & 15;

    const int m0 = blockIdx.y * 128;
    const int n0 = blockIdx.x * 128;

    __shared__ __align__(16) bf16 As[128 * 64];
    __shared__ __align__(16) bf16 Bs[128 * 64];

    floatx4 acc[4][4];
    #pragma unroll
    for (int i = 0; i < 4; i++)
        #pragma unroll
        for (int j = 0; j < 4; j++) acc[i][j] = (floatx4){0.f, 0.f, 0.f, 0.f};

    const bf16* ga0 = A + (size_t)(m0 + wave * 32 + (lane >> 3)) * GK + (lane & 7) * 8;
    const bf16* gb0 = B + (size_t)(n0 + wave * 32 + (lane >> 3)) * GK + (lane & 7) * 8;
    bf16* la = &As[(wave * 32) * 64];
    bf16* lb = &Bs[(wave * 32) * 64];

    for (int kt = 0; kt < GK; kt += 64) {
        #pragma unroll
        for (int i = 0; i < 4; i++) {
            GLDS16(ga0 + kt + (size_t)i * 8 * GK, la + i * 8 * 64);
            GLDS16(gb0 + kt + (size_t)i * 8 * GK, lb + i * 8 * 64);
        }
        __syncthreads();
        #pragma unroll
        for (int ks = 0; ks < 2; ks++) {
            bf16x8 af[4], bfr[4];
            #pragma unroll
            for (int t = 0; t < 4; t++) {
                af[t]  = *(const bf16x8*)(&As[(wm + t * 16 + lcol) * 64 + ks * 32 + lrow * 8]);
                bfr[t] = *(const bf16x8*)(&Bs[(wn + t * 16 + lcol) * 64 + ks * 32 + lrow * 8]);
            }
            #pragma unroll
            for (int mt = 0; mt < 4; mt++)
                #pragma unroll
                for (int nt = 0; nt < 4; nt++)
                    acc[mt][nt] = __builtin_amdgcn_mfma_f32_16x16x32_bf16(af[mt], bfr[nt], acc[mt][nt], 0, 0, 0);
        }
        __syncthreads();
    }

    if (bz < 2) {
        // Q/K with fused RoPE (d' = nt*16+lcol within head; partner lane lcol^1)
        bf16* __restrict__ C = bz ? Kw : Qw;
        const bool odd = (lcol & 1);
        #pragma unroll
        for (int mt = 0; mt < 4; mt++)
            #pragma unroll
            for (int nt = 0; nt < 4; nt++) {
                int i = (nt * 16 + lcol) >> 1;   // freq index 0..31
                #pragma unroll
                for (int r = 0; r < 4; r++) {
                    float v  = acc[mt][nt][r];
                    float pv = __shfl_xor(v, 1, 64);
                    int s = m0 + wm + mt * 16 + lrow * 4 + r;
                    float c  = cosp[s * 32 + i];
                    float sn = sinp[s * 32 + i];
                    float ov = odd ? (pv * sn + v * c) : (v * c - pv * sn);
                    C[(size_t)s * GN + n0 + wn + nt * 16 + lcol] = (bf16)ov;
                }
            }
    } else {
        // V: transposed store VT[col][s] (L2 coalesces; WRITE_SIZE clean in r8)
        #pragma unroll
        for (int mt = 0; mt < 4; mt++)
            #pragma unroll
            for (int nt = 0; nt < 4; nt++) {
                int col = n0 + wn + nt * 16 + lcol;
                int s   = m0 + wm + mt * 16 + lrow * 4;
                bf16x4 ov = { (bf16)acc[mt][nt][0], (bf16)acc[mt][nt][1],
                              (bf16)acc[mt][nt][2], (bf16)acc[mt][nt][3] };
                *(bf16x4*)(&VTw[(size_t)col * S_LEN + s]) = ov;
            }
    }
}

// ---------------------------------------------------------------------------
// Flash attention v5 (unchanged from r7): parity-split + shared-K dual-q.
// ---------------------------------------------------------------------------
__launch_bounds__(256, 4)
__global__ void flash_attn(const bf16* __restrict__ Q, const bf16* __restrict__ K,
                           const bf16* __restrict__ VT,
                           float* __restrict__ O0, float* __restrict__ O1,
                           float* __restrict__ L0, float* __restrict__ L1)
{
    const int pi   = blockIdx.x >> 1;
    const int p    = blockIdx.x & 1;
    const int h    = blockIdx.y;
    const int tid  = threadIdx.x;
    const int wave = tid >> 6;
    const int lane = tid & 63;
    const int lrow = lane >> 4;
    const int lcol = lane & 15;

    const int qtA = pi;
    const int qtB = 63 - pi;

    float* __restrict__ Op = p ? O1 : O0;
    float* __restrict__ Lp = p ? L1 : L0;

    __shared__ __align__(16) bf16 Ks[2][64 * FST];
    __shared__ __align__(16) bf16 Vs[2][64 * FST];

    const float sc2 = 0.125f * 1.44269504088896340736f;

    const int q0A = qtA * 64 + wave * 16;
    const int q0B = qtB * 64 + wave * 16;

    const bf16* qpA = Q + (size_t)(q0A + lcol) * DM + h * HD;
    const bf16* qpB = Q + (size_t)(q0B + lcol) * DM + h * HD;
    bf16x8 qfA[2], qfB[2];
    qfA[0] = *(const bf16x8*)(qpA + 0 + lrow * 8);
    qfA[1] = *(const bf16x8*)(qpA + 32 + lrow * 8);
    qfB[0] = *(const bf16x8*)(qpB + 0 + lrow * 8);
    qfB[1] = *(const bf16x8*)(qpB + 32 + lrow * 8);

    float lA = 0.f, lB = 0.f;
    floatx4 oaccA[4], oaccB[4];
    #pragma unroll
    for (int nt = 0; nt < 4; nt++) {
        oaccA[nt] = (floatx4){0.f, 0.f, 0.f, 0.f};
        oaccB[nt] = (floatx4){0.f, 0.f, 0.f, 0.f};
    }

    const int  srow = tid >> 3;
    const int  sch  = (tid & 7) * 8;
    const bf16* kp  = K  + (size_t)srow * DM + h * HD + sch;
    const bf16* vp  = VT + (size_t)(h * HD + srow) * S_LEN + sch;
    const int  wof  = srow * FST + sch;

    {
        size_t ko = (size_t)p * 64 * DM;
        size_t vo = (size_t)p * 64;
        uint4 a = *(const uint4*)(kp + ko);
        uint4 b = *(const uint4*)(kp + ko + (size_t)32 * DM);
        uint4 c = *(const uint4*)(vp + vo);
        uint4 d = *(const uint4*)(vp + vo + (size_t)32 * S_LEN);
        *(uint4*)(&Ks[0][wof])            = a;
        *(uint4*)(&Ks[0][wof + 32 * FST]) = b;
        *(uint4*)(&Vs[0][wof])            = c;
        *(uint4*)(&Vs[0][wof + 32 * FST]) = d;
    }
    __syncthreads();

    uint4 kr0, kr1, vr0, vr1;
    for (int t = p; t <= qtB; t += 2) {
        const int  cur  = ((t - p) >> 1) & 1;
        const bool more = (t + 2 <= qtB);
        const bool actA = (t <= qtA);

        if (more) {
            size_t ko = (size_t)(t + 2) * 64 * DM;
            size_t vo = (size_t)(t + 2) * 64;
            kr0 = *(const uint4*)(kp + ko);
            kr1 = *(const uint4*)(kp + ko + (size_t)32 * DM);
            vr0 = *(const uint4*)(vp + vo);
            vr1 = *(const uint4*)(vp + vo + (size_t)32 * S_LEN);
        }

        short4v pbA[4], pbB[4];
        const bool diagA = (t == qtA);
        const bool diagB = (t == qtB);
        #pragma unroll
        for (int nt = 0; nt < 4; nt++) {
            floatx4 zB = (floatx4){0.f, 0.f, 0.f, 0.f};
            floatx4 zA = (floatx4){0.f, 0.f, 0.f, 0.f};
            #pragma unroll
            for (int ks = 0; ks < 2; ks++) {
                bf16x8 kf = *(const bf16x8*)(&Ks[cur][(nt * 16 + lcol) * FST + ks * 32 + lrow * 8]);
                zB = __builtin_amdgcn_mfma_f32_16x16x32_bf16(kf, qfB[ks], zB, 0, 0, 0);
                if (actA)
                    zA = __builtin_amdgcn_mfma_f32_16x16x32_bf16(kf, qfA[ks], zA, 0, 0, 0);
            }
            if (diagB) {
                #pragma unroll
                for (int r = 0; r < 4; r++) {
                    int kg = t * 64 + nt * 16 + lrow * 4 + r;
                    float pr = exp2f(zB[r] * sc2);
                    if (kg > q0B + lcol) pr = 0.f;
                    zB[r] = pr; lB += pr;
                }
            } else {
                #pragma unroll
                for (int r = 0; r < 4; r++) {
                    float pr = exp2f(zB[r] * sc2);
                    zB[r] = pr; lB += pr;
                }
            }
            bf16x4 pvB = { (bf16)zB[0], (bf16)zB[1], (bf16)zB[2], (bf16)zB[3] };
            pbB[nt] = __builtin_bit_cast(short4v, pvB);
            if (actA) {
                if (diagA) {
                    #pragma unroll
                    for (int r = 0; r < 4; r++) {
                        int kg = t * 64 + nt * 16 + lrow * 4 + r;
                        float pr = exp2f(zA[r] * sc2);
                        if (kg > q0A + lcol) pr = 0.f;
                        zA[r] = pr; lA += pr;
                    }
                } else {
                    #pragma unroll
                    for (int r = 0; r < 4; r++) {
                        float pr = exp2f(zA[r] * sc2);
                        zA[r] = pr; lA += pr;
                    }
                }
                bf16x4 pvA = { (bf16)zA[0], (bf16)zA[1], (bf16)zA[2], (bf16)zA[3] };
                pbA[nt] = __builtin_bit_cast(short4v, pvA);
            }
        }

        #pragma unroll
        for (int nt = 0; nt < 4; nt++)
            #pragma unroll
            for (int kt = 0; kt < 4; kt++) {
                bf16x4 va = *(const bf16x4*)(&Vs[cur][(nt * 16 + lcol) * FST + kt * 16 + lrow * 4]);
                short4v vas = __builtin_bit_cast(short4v, va);
                oaccB[nt] = __builtin_amdgcn_mfma_f32_16x16x16bf16_1k(vas, pbB[kt], oaccB[nt], 0, 0, 0);
                if (actA)
                    oaccA[nt] = __builtin_amdgcn_mfma_f32_16x16x16bf16_1k(vas, pbA[kt], oaccA[nt], 0, 0, 0);
            }

        if (more) {
            int nxt = cur ^ 1;
            *(uint4*)(&Ks[nxt][wof])            = kr0;
            *(uint4*)(&Ks[nxt][wof + 32 * FST]) = kr1;
            *(uint4*)(&Vs[nxt][wof])            = vr0;
            *(uint4*)(&Vs[nxt][wof + 32 * FST]) = vr1;
        }
        __syncthreads();
    }

    lA += __shfl_xor(lA, 16, 64);
    lA += __shfl_xor(lA, 32, 64);
    lB += __shfl_xor(lB, 16, 64);
    lB += __shfl_xor(lB, 32, 64);
    if (lrow == 0) {
        Lp[h * S_LEN + q0A + lcol] = lA;
        Lp[h * S_LEN + q0B + lcol] = lB;
    }
    #pragma unroll
    for (int nt = 0; nt < 4; nt++) {
        *(floatx4*)(&Op[(size_t)(q0A + lcol) * DM + h * HD + nt * 16 + lrow * 4]) = oaccA[nt];
        *(floatx4*)(&Op[(size_t)(q0B + lcol) * DM + h * HD + nt * 16 + lrow * 4]) = oaccB[nt];
    }
}

// ---------------------------------------------------------------------------
// Fused output projection: A = (O0+O1)/(l0+l1) combined during staging
// (fp32 partials), B = wo bf16 (pre-converted), C = out fp32.
// ---------------------------------------------------------------------------
__launch_bounds__(256)
__global__ void gemm_out(const float* __restrict__ O0, const float* __restrict__ O1,
                         const float* __restrict__ L0, const float* __restrict__ L1,
                         const bf16* __restrict__ wo, float* __restrict__ out)
{
    const int tid  = threadIdx.x;
    const int wave = tid >> 6;
    const int lane = tid & 63;
    const int wm   = (wave >> 1) * 64;
    const int wn   = (wave & 1) * 64;
    const int lrow = lane >> 4;
    const int lcol = lane & 15;

    const int m0 = blockIdx.y * 128;
    const int n0 = blockIdx.x * 128;

    __shared__ __align__(16) bf16 As[128 * LDST];
    __shared__ __align__(16) bf16 Bs[128 * LDST];

    floatx4 acc[4][4];
    #pragma unroll
    for (int i = 0; i < 4; i++)
        #pragma unroll
        for (int j = 0; j < 4; j++) acc[i][j] = (floatx4){0.f, 0.f, 0.f, 0.f};

    for (int kt = 0; kt < GK; kt += 64) {
        #pragma unroll
        for (int i = 0; i < 4; i++) {
            int idx = i * 256 + tid;
            int row = idx >> 3;
            int ch  = (idx & 7) * 8;
            int s   = m0 + row;
            int hh  = (kt + ch) >> 6;
            float rl = 1.f / (L0[hh * S_LEN + s] + L1[hh * S_LEN + s]);
            const float* a0p = &O0[(size_t)s * GK + kt + ch];
            const float* a1p = &O1[(size_t)s * GK + kt + ch];
            float4 a0 = *(const float4*)(a0p), a1 = *(const float4*)(a0p + 4);
            float4 b0 = *(const float4*)(a1p), b1 = *(const float4*)(a1p + 4);
            bf16x8 av = { (bf16)((a0.x + b0.x) * rl), (bf16)((a0.y + b0.y) * rl),
                          (bf16)((a0.z + b0.z) * rl), (bf16)((a0.w + b0.w) * rl),
                          (bf16)((a1.x + b1.x) * rl), (bf16)((a1.y + b1.y) * rl),
                          (bf16)((a1.z + b1.z) * rl), (bf16)((a1.w + b1.w) * rl) };
            *(bf16x8*)(&As[row * LDST + ch]) = av;
            *(uint4*)(&Bs[row * LDST + ch]) =
                *(const uint4*)(&wo[(size_t)(n0 + row) * GK + kt + ch]);
        }
        __syncthreads();
        #pragma unroll
        for (int ks = 0; ks < 2; ks++) {
            bf16x8 af[4], bfr[4];
            #pragma unroll
            for (int t = 0; t < 4; t++) {
                af[t]  = *(const bf16x8*)(&As[(wm + t * 16 + lcol) * LDST + ks * 32 + lrow * 8]);
                bfr[t] = *(const bf16x8*)(&Bs[(wn + t * 16 + lcol) * LDST + ks * 32 + lrow * 8]);
            }
            #pragma unroll
            for (int mt = 0; mt < 4; mt++)
                #pragma unroll
                for (int nt = 0; nt < 4; nt++)
                    acc[mt][nt] = __builtin_amdgcn_mfma_f32_16x16x32_bf16(af[mt], bfr[nt], acc[mt][nt], 0, 0, 0);
        }
        __syncthreads();
    }

    #pragma unroll
    for (int mt = 0; mt < 4; mt++)
        #pragma unroll
        for (int nt = 0; nt < 4; nt++)
            #pragma unroll
            for (int r = 0; r < 4; r++) {
                int row = m0 + wm + mt * 16 + lrow * 4 + r;
                int col = n0 + wn + nt * 16 + lcol;
                out[(size_t)row * GN + col] = acc[mt][nt][r];
            }
}

// ---------------------------------------------------------------------------
extern "C" void kernel_launch(void* const* d_in, const int* in_sizes, int n_in,
                              void* d_out, int out_size, void* d_ws, size_t ws_size,
                              hipStream_t stream) {
    const float* x    = (const float*)d_in[0];
    const float* cosp = (const float*)d_in[1];
    const float* sinp = (const float*)d_in[2];
    const float* wq   = (const float*)d_in[4];
    const float* wk   = (const float*)d_in[5];
    const float* wv   = (const float*)d_in[6];
    const float* wo   = (const float*)d_in[7];
    float* out = (float*)d_out;

    const size_t SD = (size_t)S_LEN * DM;   // 4M elems
    const size_t DD = (size_t)DM * DM;      // 1M elems
    bf16* xb  = (bf16*)d_ws;                // 4M bf16
    bf16* wqb = xb + SD;
    bf16* wkb = wqb + DD;
    bf16* wvb = wkb + DD;
    bf16* wob = wvb + DD;
    bf16* Qw  = wob + DD;                   // 4M bf16 each
    bf16* Kw  = Qw + SD;
    bf16* VTw = Kw + SD;
    float* O0f = (float*)(VTw + SD);        // 4M fp32 each
    float* O1f = O0f + SD;
    float* L0f = O1f + SD;                  // 64K fp32 each
    float* L1f = L0f + (size_t)S_LEN * NH;

    // 1) fp32 -> bf16 (x + 4 weights)
    cvt_bf16<<<8192, 256, 0, stream>>>(x, wq, wk, wv, wo, xb);
    // 2) QKV projections + RoPE + V-transpose fused (bf16 staging)
    gemm_qkv<<<dim3(GN / 128, GM / 128, 3), 256, 0, stream>>>(
        xb, wqb, wkb, wvb, cosp, sinp, Qw, Kw, VTw);
    // 3) flash attention (parity-split partials)
    flash_attn<<<dim3(64, NH), 256, 0, stream>>>(Qw, Kw, VTw, O0f, O1f, L0f, L1f);
    // 4) output projection + combine fused
    gemm_out<<<dim3(GN / 128, GM / 128, 1), 256, 0, stream>>>(
        O0f, O1f, L0f, L1f, wob, out);
}

// Round 10
// 297.194 us; speedup vs baseline: 1.1318x; 1.0608x over previous
//
#include <hip/hip_runtime.h>
#include <hip/hip_bf16.h>
#include <math.h>

typedef __bf16 bf16;
typedef __bf16 bf16x4 __attribute__((ext_vector_type(4)));
typedef __bf16 bf16x8 __attribute__((ext_vector_type(8)));
typedef float floatx4 __attribute__((ext_vector_type(4)));
typedef short short4v __attribute__((ext_vector_type(4)));

#define S_LEN 4096
#define DM 1024
#define NH 16
#define HD 64

#define GM 4096
#define GN 1024
#define GK 1024
#define FST 68     // flash LDS row stride (zero measured conflicts, r3-r9)

// async global->LDS, 16B per lane; lds base wave-uniform (m97/m104)
#define GLDS16(gp, lp) __builtin_amdgcn_global_load_lds( \
    (const __attribute__((address_space(1))) void*)(gp), \
    (__attribute__((address_space(3))) void*)(lp), 16, 0, 0)

// ---------------------------------------------------------------------------
// fp32 -> bf16: x (4M) + wq/wk/wv/wo (1M each) into contiguous ws.
// ---------------------------------------------------------------------------
__global__ void cvt_bf16(const float* __restrict__ x,  const float* __restrict__ wq,
                         const float* __restrict__ wk, const float* __restrict__ wv,
                         const float* __restrict__ wo, bf16* __restrict__ dst)
{
    size_t i4 = ((size_t)blockIdx.x * 256 + threadIdx.x) * 4;   // 8M elems total
    const float* src; size_t off;
    const size_t M1 = (size_t)1 << 20;
    if      (i4 < 4 * M1) { src = x;  off = i4;          }
    else if (i4 < 5 * M1) { src = wq; off = i4 - 4 * M1; }
    else if (i4 < 6 * M1) { src = wk; off = i4 - 5 * M1; }
    else if (i4 < 7 * M1) { src = wv; off = i4 - 6 * M1; }
    else                  { src = wo; off = i4 - 7 * M1; }
    float4 v = *(const float4*)(src + off);
    bf16x4 o = { (bf16)v.x, (bf16)v.y, (bf16)v.z, (bf16)v.w };
    *(bf16x4*)(&dst[i4]) = o;
}

// ---------------------------------------------------------------------------
// Fused QKV GEMM (bf16 in, GLDS16 staging). C = x*W^T. Epilogue per z:
//   z=0/1 (Q/K): RoPE in-register (pair via shfl_xor(1)) -> Qw/Kw bf16.
//   z=2   (V):   transposed store -> VTw[d_global][s] (packed bf16x4).
// ---------------------------------------------------------------------------
__launch_bounds__(256)
__global__ void gemm_qkv(const bf16* __restrict__ A,
                         const bf16* __restrict__ B0, const bf16* __restrict__ B1,
                         const bf16* __restrict__ B2,
                         const float* __restrict__ cosp, const float* __restrict__ sinp,
                         bf16* __restrict__ Qw, bf16* __restrict__ Kw,
                         bf16* __restrict__ VTw)
{
    const int bz = blockIdx.z;
    const bf16* __restrict__ B = (bz == 0) ? B0 : (bz == 1 ? B1 : B2);

    const int tid  = threadIdx.x;
    const int wave = tid >> 6;
    const int lane = tid & 63;
    const int wm   = (wave >> 1) * 64;
    const int wn   = (wave & 1) * 64;
    const int lrow = lane >> 4;
    const int lcol = lane & 15;

    const int m0 = blockIdx.y * 128;
    const int n0 = blockIdx.x * 128;

    __shared__ __align__(16) bf16 As[128 * 64];
    __shared__ __align__(16) bf16 Bs[128 * 64];

    floatx4 acc[4][4];
    #pragma unroll
    for (int i = 0; i < 4; i++)
        #pragma unroll
        for (int j = 0; j < 4; j++) acc[i][j] = (floatx4){0.f, 0.f, 0.f, 0.f};

    const bf16* ga0 = A + (size_t)(m0 + wave * 32 + (lane >> 3)) * GK + (lane & 7) * 8;
    const bf16* gb0 = B + (size_t)(n0 + wave * 32 + (lane >> 3)) * GK + (lane & 7) * 8;
    bf16* la = &As[(wave * 32) * 64];
    bf16* lb = &Bs[(wave * 32) * 64];

    for (int kt = 0; kt < GK; kt += 64) {
        #pragma unroll
        for (int i = 0; i < 4; i++) {
            GLDS16(ga0 + kt + (size_t)i * 8 * GK, la + i * 8 * 64);
            GLDS16(gb0 + kt + (size_t)i * 8 * GK, lb + i * 8 * 64);
        }
        __syncthreads();
        #pragma unroll
        for (int ks = 0; ks < 2; ks++) {
            bf16x8 af[4], bfr[4];
            #pragma unroll
            for (int t = 0; t < 4; t++) {
                af[t]  = *(const bf16x8*)(&As[(wm + t * 16 + lcol) * 64 + ks * 32 + lrow * 8]);
                bfr[t] = *(const bf16x8*)(&Bs[(wn + t * 16 + lcol) * 64 + ks * 32 + lrow * 8]);
            }
            #pragma unroll
            for (int mt = 0; mt < 4; mt++)
                #pragma unroll
                for (int nt = 0; nt < 4; nt++)
                    acc[mt][nt] = __builtin_amdgcn_mfma_f32_16x16x32_bf16(af[mt], bfr[nt], acc[mt][nt], 0, 0, 0);
        }
        __syncthreads();
    }

    if (bz < 2) {
        bf16* __restrict__ C = bz ? Kw : Qw;
        const bool odd = (lcol & 1);
        #pragma unroll
        for (int mt = 0; mt < 4; mt++)
            #pragma unroll
            for (int nt = 0; nt < 4; nt++) {
                int i = (nt * 16 + lcol) >> 1;   // freq index 0..31
                #pragma unroll
                for (int r = 0; r < 4; r++) {
                    float v  = acc[mt][nt][r];
                    float pv = __shfl_xor(v, 1, 64);
                    int s = m0 + wm + mt * 16 + lrow * 4 + r;
                    float c  = cosp[s * 32 + i];
                    float sn = sinp[s * 32 + i];
                    float ov = odd ? (pv * sn + v * c) : (v * c - pv * sn);
                    C[(size_t)s * GN + n0 + wn + nt * 16 + lcol] = (bf16)ov;
                }
            }
    } else {
        #pragma unroll
        for (int mt = 0; mt < 4; mt++)
            #pragma unroll
            for (int nt = 0; nt < 4; nt++) {
                int col = n0 + wn + nt * 16 + lcol;
                int s   = m0 + wm + mt * 16 + lrow * 4;
                bf16x4 ov = { (bf16)acc[mt][nt][0], (bf16)acc[mt][nt][1],
                              (bf16)acc[mt][nt][2], (bf16)acc[mt][nt][3] };
                *(bf16x4*)(&VTw[(size_t)col * S_LEN + s]) = ov;
            }
    }
}

// ---------------------------------------------------------------------------
// Flash attention v5 (unchanged from r7/r9): parity-split + shared-K dual-q.
// ---------------------------------------------------------------------------
__launch_bounds__(256, 4)
__global__ void flash_attn(const bf16* __restrict__ Q, const bf16* __restrict__ K,
                           const bf16* __restrict__ VT,
                           float* __restrict__ O0, float* __restrict__ O1,
                           float* __restrict__ L0, float* __restrict__ L1)
{
    const int pi   = blockIdx.x >> 1;
    const int p    = blockIdx.x & 1;
    const int h    = blockIdx.y;
    const int tid  = threadIdx.x;
    const int wave = tid >> 6;
    const int lane = tid & 63;
    const int lrow = lane >> 4;
    const int lcol = lane & 15;

    const int qtA = pi;
    const int qtB = 63 - pi;

    float* __restrict__ Op = p ? O1 : O0;
    float* __restrict__ Lp = p ? L1 : L0;

    __shared__ __align__(16) bf16 Ks[2][64 * FST];
    __shared__ __align__(16) bf16 Vs[2][64 * FST];

    const float sc2 = 0.125f * 1.44269504088896340736f;

    const int q0A = qtA * 64 + wave * 16;
    const int q0B = qtB * 64 + wave * 16;

    const bf16* qpA = Q + (size_t)(q0A + lcol) * DM + h * HD;
    const bf16* qpB = Q + (size_t)(q0B + lcol) * DM + h * HD;
    bf16x8 qfA[2], qfB[2];
    qfA[0] = *(const bf16x8*)(qpA + 0 + lrow * 8);
    qfA[1] = *(const bf16x8*)(qpA + 32 + lrow * 8);
    qfB[0] = *(const bf16x8*)(qpB + 0 + lrow * 8);
    qfB[1] = *(const bf16x8*)(qpB + 32 + lrow * 8);

    float lA = 0.f, lB = 0.f;
    floatx4 oaccA[4], oaccB[4];
    #pragma unroll
    for (int nt = 0; nt < 4; nt++) {
        oaccA[nt] = (floatx4){0.f, 0.f, 0.f, 0.f};
        oaccB[nt] = (floatx4){0.f, 0.f, 0.f, 0.f};
    }

    const int  srow = tid >> 3;
    const int  sch  = (tid & 7) * 8;
    const bf16* kp  = K  + (size_t)srow * DM + h * HD + sch;
    const bf16* vp  = VT + (size_t)(h * HD + srow) * S_LEN + sch;
    const int  wof  = srow * FST + sch;

    {
        size_t ko = (size_t)p * 64 * DM;
        size_t vo = (size_t)p * 64;
        uint4 a = *(const uint4*)(kp + ko);
        uint4 b = *(const uint4*)(kp + ko + (size_t)32 * DM);
        uint4 c = *(const uint4*)(vp + vo);
        uint4 d = *(const uint4*)(vp + vo + (size_t)32 * S_LEN);
        *(uint4*)(&Ks[0][wof])            = a;
        *(uint4*)(&Ks[0][wof + 32 * FST]) = b;
        *(uint4*)(&Vs[0][wof])            = c;
        *(uint4*)(&Vs[0][wof + 32 * FST]) = d;
    }
    __syncthreads();

    uint4 kr0, kr1, vr0, vr1;
    for (int t = p; t <= qtB; t += 2) {
        const int  cur  = ((t - p) >> 1) & 1;
        const bool more = (t + 2 <= qtB);
        const bool actA = (t <= qtA);

        if (more) {
            size_t ko = (size_t)(t + 2) * 64 * DM;
            size_t vo = (size_t)(t + 2) * 64;
            kr0 = *(const uint4*)(kp + ko);
            kr1 = *(const uint4*)(kp + ko + (size_t)32 * DM);
            vr0 = *(const uint4*)(vp + vo);
            vr1 = *(const uint4*)(vp + vo + (size_t)32 * S_LEN);
        }

        short4v pbA[4], pbB[4];
        const bool diagA = (t == qtA);
        const bool diagB = (t == qtB);
        #pragma unroll
        for (int nt = 0; nt < 4; nt++) {
            floatx4 zB = (floatx4){0.f, 0.f, 0.f, 0.f};
            floatx4 zA = (floatx4){0.f, 0.f, 0.f, 0.f};
            #pragma unroll
            for (int ks = 0; ks < 2; ks++) {
                bf16x8 kf = *(const bf16x8*)(&Ks[cur][(nt * 16 + lcol) * FST + ks * 32 + lrow * 8]);
                zB = __builtin_amdgcn_mfma_f32_16x16x32_bf16(kf, qfB[ks], zB, 0, 0, 0);
                if (actA)
                    zA = __builtin_amdgcn_mfma_f32_16x16x32_bf16(kf, qfA[ks], zA, 0, 0, 0);
            }
            if (diagB) {
                #pragma unroll
                for (int r = 0; r < 4; r++) {
                    int kg = t * 64 + nt * 16 + lrow * 4 + r;
                    float pr = exp2f(zB[r] * sc2);
                    if (kg > q0B + lcol) pr = 0.f;
                    zB[r] = pr; lB += pr;
                }
            } else {
                #pragma unroll
                for (int r = 0; r < 4; r++) {
                    float pr = exp2f(zB[r] * sc2);
                    zB[r] = pr; lB += pr;
                }
            }
            bf16x4 pvB = { (bf16)zB[0], (bf16)zB[1], (bf16)zB[2], (bf16)zB[3] };
            pbB[nt] = __builtin_bit_cast(short4v, pvB);
            if (actA) {
                if (diagA) {
                    #pragma unroll
                    for (int r = 0; r < 4; r++) {
                        int kg = t * 64 + nt * 16 + lrow * 4 + r;
                        float pr = exp2f(zA[r] * sc2);
                        if (kg > q0A + lcol) pr = 0.f;
                        zA[r] = pr; lA += pr;
                    }
                } else {
                    #pragma unroll
                    for (int r = 0; r < 4; r++) {
                        float pr = exp2f(zA[r] * sc2);
                        zA[r] = pr; lA += pr;
                    }
                }
                bf16x4 pvA = { (bf16)zA[0], (bf16)zA[1], (bf16)zA[2], (bf16)zA[3] };
                pbA[nt] = __builtin_bit_cast(short4v, pvA);
            }
        }

        #pragma unroll
        for (int nt = 0; nt < 4; nt++)
            #pragma unroll
            for (int kt = 0; kt < 4; kt++) {
                bf16x4 va = *(const bf16x4*)(&Vs[cur][(nt * 16 + lcol) * FST + kt * 16 + lrow * 4]);
                short4v vas = __builtin_bit_cast(short4v, va);
                oaccB[nt] = __builtin_amdgcn_mfma_f32_16x16x16bf16_1k(vas, pbB[kt], oaccB[nt], 0, 0, 0);
                if (actA)
                    oaccA[nt] = __builtin_amdgcn_mfma_f32_16x16x16bf16_1k(vas, pbA[kt], oaccA[nt], 0, 0, 0);
            }

        if (more) {
            int nxt = cur ^ 1;
            *(uint4*)(&Ks[nxt][wof])            = kr0;
            *(uint4*)(&Ks[nxt][wof + 32 * FST]) = kr1;
            *(uint4*)(&Vs[nxt][wof])            = vr0;
            *(uint4*)(&Vs[nxt][wof + 32 * FST]) = vr1;
        }
        __syncthreads();
    }

    lA += __shfl_xor(lA, 16, 64);
    lA += __shfl_xor(lA, 32, 64);
    lB += __shfl_xor(lB, 16, 64);
    lB += __shfl_xor(lB, 32, 64);
    if (lrow == 0) {
        Lp[h * S_LEN + q0A + lcol] = lA;
        Lp[h * S_LEN + q0B + lcol] = lB;
    }
    #pragma unroll
    for (int nt = 0; nt < 4; nt++) {
        *(floatx4*)(&Op[(size_t)(q0A + lcol) * DM + h * HD + nt * 16 + lrow * 4]) = oaccA[nt];
        *(floatx4*)(&Op[(size_t)(q0B + lcol) * DM + h * HD + nt * 16 + lrow * 4]) = oaccB[nt];
    }
}

// ---------------------------------------------------------------------------
// Combine: Aw = (O0 + O1) / (l0 + l1), fp32 -> bf16. (r7-verified, ~12 us)
// ---------------------------------------------------------------------------
__global__ void combine_kernel(const float* __restrict__ O0, const float* __restrict__ O1,
                               const float* __restrict__ L0, const float* __restrict__ L1,
                               bf16* __restrict__ Aw)
{
    int i4 = (blockIdx.x * 256 + threadIdx.x) * 4;   // 4M elems
    int q = i4 >> 10;
    int c = i4 & 1023;
    int h = c >> 6;
    float rl = 1.f / (L0[h * S_LEN + q] + L1[h * S_LEN + q]);
    float4 a = *(const float4*)(O0 + i4);
    float4 b = *(const float4*)(O1 + i4);
    bf16x4 o = { (bf16)((a.x + b.x) * rl), (bf16)((a.y + b.y) * rl),
                 (bf16)((a.z + b.z) * rl), (bf16)((a.w + b.w) * rl) };
    *(bf16x4*)(&Aw[i4]) = o;
}

// ---------------------------------------------------------------------------
// Output projection: out[M,N] = Aw[M,K] * wo[N,K]^T, bf16 in, fp32 out.
// 64x128 (MxN) tiles -> grid (8,64) = 512 blocks = 2/CU. GLDS16 staging.
// Waves 2x2: wave owns 32(M) x 64(N) = 2x4 MFMA tiles.
// ---------------------------------------------------------------------------
__launch_bounds__(256)
__global__ void gemm_out(const bf16* __restrict__ A, const bf16* __restrict__ B,
                         float* __restrict__ out)
{
    const int tid  = threadIdx.x;
    const int wave = tid >> 6;
    const int lane = tid & 63;
    const int wm   = (wave >> 1) * 32;
    const int wn   = (wave & 1) * 64;
    const int lrow = lane >> 4;
    const int lcol = lane & 15;

    const int m0 = blockIdx.y * 64;
    const int n0 = blockIdx.x * 128;

    __shared__ __align__(16) bf16 As[64 * 64];
    __shared__ __align__(16) bf16 Bs[128 * 64];

    floatx4 acc[2][4];
    #pragma unroll
    for (int i = 0; i < 2; i++)
        #pragma unroll
        for (int j = 0; j < 4; j++) acc[i][j] = (floatx4){0.f, 0.f, 0.f, 0.f};

    // wave w stages A rows [w*16, w*16+16) (2 instrs), B rows [w*32, +32) (4)
    const bf16* ga0 = A + (size_t)(m0 + wave * 16 + (lane >> 3)) * GK + (lane & 7) * 8;
    const bf16* gb0 = B + (size_t)(n0 + wave * 32 + (lane >> 3)) * GK + (lane & 7) * 8;
    bf16* la = &As[(wave * 16) * 64];
    bf16* lb = &Bs[(wave * 32) * 64];

    for (int kt = 0; kt < GK; kt += 64) {
        #pragma unroll
        for (int i = 0; i < 2; i++)
            GLDS16(ga0 + kt + (size_t)i * 8 * GK, la + i * 8 * 64);
        #pragma unroll
        for (int i = 0; i < 4; i++)
            GLDS16(gb0 + kt + (size_t)i * 8 * GK, lb + i * 8 * 64);
        __syncthreads();
        #pragma unroll
        for (int ks = 0; ks < 2; ks++) {
            bf16x8 af[2], bfr[4];
            #pragma unroll
            for (int t = 0; t < 2; t++)
                af[t]  = *(const bf16x8*)(&As[(wm + t * 16 + lcol) * 64 + ks * 32 + lrow * 8]);
            #pragma unroll
            for (int t = 0; t < 4; t++)
                bfr[t] = *(const bf16x8*)(&Bs[(wn + t * 16 + lcol) * 64 + ks * 32 + lrow * 8]);
            #pragma unroll
            for (int mt = 0; mt < 2; mt++)
                #pragma unroll
                for (int nt = 0; nt < 4; nt++)
                    acc[mt][nt] = __builtin_amdgcn_mfma_f32_16x16x32_bf16(af[mt], bfr[nt], acc[mt][nt], 0, 0, 0);
        }
        __syncthreads();
    }

    #pragma unroll
    for (int mt = 0; mt < 2; mt++)
        #pragma unroll
        for (int nt = 0; nt < 4; nt++)
            #pragma unroll
            for (int r = 0; r < 4; r++) {
                int row = m0 + wm + mt * 16 + lrow * 4 + r;
                int col = n0 + wn + nt * 16 + lcol;
                out[(size_t)row * GN + col] = acc[mt][nt][r];
            }
}

// ---------------------------------------------------------------------------
extern "C" void kernel_launch(void* const* d_in, const int* in_sizes, int n_in,
                              void* d_out, int out_size, void* d_ws, size_t ws_size,
                              hipStream_t stream) {
    const float* x    = (const float*)d_in[0];
    const float* cosp = (const float*)d_in[1];
    const float* sinp = (const float*)d_in[2];
    const float* wq   = (const float*)d_in[4];
    const float* wk   = (const float*)d_in[5];
    const float* wv   = (const float*)d_in[6];
    const float* wo   = (const float*)d_in[7];
    float* out = (float*)d_out;

    const size_t SD = (size_t)S_LEN * DM;   // 4M elems
    const size_t DD = (size_t)DM * DM;      // 1M elems
    bf16* xb  = (bf16*)d_ws;                // 4M bf16
    bf16* wqb = xb + SD;
    bf16* wkb = wqb + DD;
    bf16* wvb = wkb + DD;
    bf16* wob = wvb + DD;
    bf16* Qw  = wob + DD;                   // 4M bf16 each
    bf16* Kw  = Qw + SD;
    bf16* VTw = Kw + SD;
    bf16* Aw  = VTw + SD;
    float* O0f = (float*)(Aw + SD);         // 4M fp32 each
    float* O1f = O0f + SD;
    float* L0f = O1f + SD;                  // 64K fp32 each
    float* L1f = L0f + (size_t)S_LEN * NH;

    // 1) fp32 -> bf16 (x + 4 weights)
    cvt_bf16<<<8192, 256, 0, stream>>>(x, wq, wk, wv, wo, xb);
    // 2) QKV projections + RoPE + V-transpose fused
    gemm_qkv<<<dim3(GN / 128, GM / 128, 3), 256, 0, stream>>>(
        xb, wqb, wkb, wvb, cosp, sinp, Qw, Kw, VTw);
    // 3) flash attention (parity-split partials)
    flash_attn<<<dim3(64, NH), 256, 0, stream>>>(Qw, Kw, VTw, O0f, O1f, L0f, L1f);
    // 4) combine partials -> bf16 Aw
    combine_kernel<<<S_LEN * DM / 1024, 256, 0, stream>>>(O0f, O1f, L0f, L1f, Aw);
    // 5) output projection (bf16 staging, 2 blocks/CU)
    gemm_out<<<dim3(GN / 128, GM / 64), 256, 0, stream>>>(Aw, wob, out);
}

// Round 11
// 287.574 us; speedup vs baseline: 1.1696x; 1.0335x over previous
//
#include <hip/hip_runtime.h>
#include <hip/hip_bf16.h>
#include <math.h>

typedef __bf16 bf16;
typedef __bf16 bf16x4 __attribute__((ext_vector_type(4)));
typedef __bf16 bf16x8 __attribute__((ext_vector_type(8)));
typedef float floatx4 __attribute__((ext_vector_type(4)));
typedef short short4v __attribute__((ext_vector_type(4)));

#define S_LEN 4096
#define DM 1024
#define NH 16
#define HD 64

#define GM 4096
#define GN 1024
#define GK 1024
#define FST 68     // flash LDS row stride (zero measured conflicts, r3-r10)

// async global->LDS, 16B per lane; lds base wave-uniform (m97/m104)
#define GLDS16(gp, lp) __builtin_amdgcn_global_load_lds( \
    (const __attribute__((address_space(1))) void*)(gp), \
    (__attribute__((address_space(3))) void*)(lp), 16, 0, 0)

// ---------------------------------------------------------------------------
// fp32 -> bf16: x (4M) + wq/wk/wv/wo (1M each) into contiguous ws.
// ---------------------------------------------------------------------------
__global__ void cvt_bf16(const float* __restrict__ x,  const float* __restrict__ wq,
                         const float* __restrict__ wk, const float* __restrict__ wv,
                         const float* __restrict__ wo, bf16* __restrict__ dst)
{
    size_t i4 = ((size_t)blockIdx.x * 256 + threadIdx.x) * 4;   // 8M elems total
    const float* src; size_t off;
    const size_t M1 = (size_t)1 << 20;
    if      (i4 < 4 * M1) { src = x;  off = i4;          }
    else if (i4 < 5 * M1) { src = wq; off = i4 - 4 * M1; }
    else if (i4 < 6 * M1) { src = wk; off = i4 - 5 * M1; }
    else if (i4 < 7 * M1) { src = wv; off = i4 - 6 * M1; }
    else                  { src = wo; off = i4 - 7 * M1; }
    float4 v = *(const float4*)(src + off);
    bf16x4 o = { (bf16)v.x, (bf16)v.y, (bf16)v.z, (bf16)v.w };
    *(bf16x4*)(&dst[i4]) = o;
}

// ---------------------------------------------------------------------------
// Fused QKV GEMM, 64x128 tiles (re-tiled r11: 6 blocks/CU for latency hiding).
// C = x*W^T. Epilogue per z:
//   z=0/1 (Q/K): RoPE in-register (pair via shfl_xor(1)) -> Qw/Kw bf16.
//   z=2   (V):   transposed store -> VTw[d_global][s] (packed bf16x4).
// ---------------------------------------------------------------------------
__launch_bounds__(256)
__global__ void gemm_qkv(const bf16* __restrict__ A,
                         const bf16* __restrict__ B0, const bf16* __restrict__ B1,
                         const bf16* __restrict__ B2,
                         const float* __restrict__ cosp, const float* __restrict__ sinp,
                         bf16* __restrict__ Qw, bf16* __restrict__ Kw,
                         bf16* __restrict__ VTw)
{
    const int bz = blockIdx.z;
    const bf16* __restrict__ B = (bz == 0) ? B0 : (bz == 1 ? B1 : B2);

    const int tid  = threadIdx.x;
    const int wave = tid >> 6;
    const int lane = tid & 63;
    const int wm   = (wave >> 1) * 32;
    const int wn   = (wave & 1) * 64;
    const int lrow = lane >> 4;
    const int lcol = lane & 15;

    const int m0 = blockIdx.y * 64;
    const int n0 = blockIdx.x * 128;

    __shared__ __align__(16) bf16 As[64 * 64];
    __shared__ __align__(16) bf16 Bs[128 * 64];

    floatx4 acc[2][4];
    #pragma unroll
    for (int i = 0; i < 2; i++)
        #pragma unroll
        for (int j = 0; j < 4; j++) acc[i][j] = (floatx4){0.f, 0.f, 0.f, 0.f};

    // wave w stages A rows [w*16,+16) (2 instrs), B rows [w*32,+32) (4 instrs)
    const bf16* ga0 = A + (size_t)(m0 + wave * 16 + (lane >> 3)) * GK + (lane & 7) * 8;
    const bf16* gb0 = B + (size_t)(n0 + wave * 32 + (lane >> 3)) * GK + (lane & 7) * 8;
    bf16* la = &As[(wave * 16) * 64];
    bf16* lb = &Bs[(wave * 32) * 64];

    for (int kt = 0; kt < GK; kt += 64) {
        #pragma unroll
        for (int i = 0; i < 2; i++)
            GLDS16(ga0 + kt + (size_t)i * 8 * GK, la + i * 8 * 64);
        #pragma unroll
        for (int i = 0; i < 4; i++)
            GLDS16(gb0 + kt + (size_t)i * 8 * GK, lb + i * 8 * 64);
        __syncthreads();
        #pragma unroll
        for (int ks = 0; ks < 2; ks++) {
            bf16x8 af[2], bfr[4];
            #pragma unroll
            for (int t = 0; t < 2; t++)
                af[t]  = *(const bf16x8*)(&As[(wm + t * 16 + lcol) * 64 + ks * 32 + lrow * 8]);
            #pragma unroll
            for (int t = 0; t < 4; t++)
                bfr[t] = *(const bf16x8*)(&Bs[(wn + t * 16 + lcol) * 64 + ks * 32 + lrow * 8]);
            #pragma unroll
            for (int mt = 0; mt < 2; mt++)
                #pragma unroll
                for (int nt = 0; nt < 4; nt++)
                    acc[mt][nt] = __builtin_amdgcn_mfma_f32_16x16x32_bf16(af[mt], bfr[nt], acc[mt][nt], 0, 0, 0);
        }
        __syncthreads();
    }

    if (bz < 2) {
        bf16* __restrict__ C = bz ? Kw : Qw;
        const bool odd = (lcol & 1);
        #pragma unroll
        for (int mt = 0; mt < 2; mt++)
            #pragma unroll
            for (int nt = 0; nt < 4; nt++) {
                int i = (nt * 16 + lcol) >> 1;   // freq index 0..31 (cols repeat per head)
                #pragma unroll
                for (int r = 0; r < 4; r++) {
                    float v  = acc[mt][nt][r];
                    float pv = __shfl_xor(v, 1, 64);
                    int s = m0 + wm + mt * 16 + lrow * 4 + r;
                    float c  = cosp[s * 32 + i];
                    float sn = sinp[s * 32 + i];
                    float ov = odd ? (pv * sn + v * c) : (v * c - pv * sn);
                    C[(size_t)s * GN + n0 + wn + nt * 16 + lcol] = (bf16)ov;
                }
            }
    } else {
        #pragma unroll
        for (int mt = 0; mt < 2; mt++)
            #pragma unroll
            for (int nt = 0; nt < 4; nt++) {
                int col = n0 + wn + nt * 16 + lcol;
                int s   = m0 + wm + mt * 16 + lrow * 4;
                bf16x4 ov = { (bf16)acc[mt][nt][0], (bf16)acc[mt][nt][1],
                              (bf16)acc[mt][nt][2], (bf16)acc[mt][nt][3] };
                *(bf16x4*)(&VTw[(size_t)col * S_LEN + s]) = ov;
            }
    }
}

// ---------------------------------------------------------------------------
// Flash attention v5 (unchanged from r7-r10): parity-split + shared-K dual-q.
// ---------------------------------------------------------------------------
__launch_bounds__(256, 4)
__global__ void flash_attn(const bf16* __restrict__ Q, const bf16* __restrict__ K,
                           const bf16* __restrict__ VT,
                           float* __restrict__ O0, float* __restrict__ O1,
                           float* __restrict__ L0, float* __restrict__ L1)
{
    const int pi   = blockIdx.x >> 1;
    const int p    = blockIdx.x & 1;
    const int h    = blockIdx.y;
    const int tid  = threadIdx.x;
    const int wave = tid >> 6;
    const int lane = tid & 63;
    const int lrow = lane >> 4;
    const int lcol = lane & 15;

    const int qtA = pi;
    const int qtB = 63 - pi;

    float* __restrict__ Op = p ? O1 : O0;
    float* __restrict__ Lp = p ? L1 : L0;

    __shared__ __align__(16) bf16 Ks[2][64 * FST];
    __shared__ __align__(16) bf16 Vs[2][64 * FST];

    const float sc2 = 0.125f * 1.44269504088896340736f;

    const int q0A = qtA * 64 + wave * 16;
    const int q0B = qtB * 64 + wave * 16;

    const bf16* qpA = Q + (size_t)(q0A + lcol) * DM + h * HD;
    const bf16* qpB = Q + (size_t)(q0B + lcol) * DM + h * HD;
    bf16x8 qfA[2], qfB[2];
    qfA[0] = *(const bf16x8*)(qpA + 0 + lrow * 8);
    qfA[1] = *(const bf16x8*)(qpA + 32 + lrow * 8);
    qfB[0] = *(const bf16x8*)(qpB + 0 + lrow * 8);
    qfB[1] = *(const bf16x8*)(qpB + 32 + lrow * 8);

    float lA = 0.f, lB = 0.f;
    floatx4 oaccA[4], oaccB[4];
    #pragma unroll
    for (int nt = 0; nt < 4; nt++) {
        oaccA[nt] = (floatx4){0.f, 0.f, 0.f, 0.f};
        oaccB[nt] = (floatx4){0.f, 0.f, 0.f, 0.f};
    }

    const int  srow = tid >> 3;
    const int  sch  = (tid & 7) * 8;
    const bf16* kp  = K  + (size_t)srow * DM + h * HD + sch;
    const bf16* vp  = VT + (size_t)(h * HD + srow) * S_LEN + sch;
    const int  wof  = srow * FST + sch;

    {
        size_t ko = (size_t)p * 64 * DM;
        size_t vo = (size_t)p * 64;
        uint4 a = *(const uint4*)(kp + ko);
        uint4 b = *(const uint4*)(kp + ko + (size_t)32 * DM);
        uint4 c = *(const uint4*)(vp + vo);
        uint4 d = *(const uint4*)(vp + vo + (size_t)32 * S_LEN);
        *(uint4*)(&Ks[0][wof])            = a;
        *(uint4*)(&Ks[0][wof + 32 * FST]) = b;
        *(uint4*)(&Vs[0][wof])            = c;
        *(uint4*)(&Vs[0][wof + 32 * FST]) = d;
    }
    __syncthreads();

    uint4 kr0, kr1, vr0, vr1;
    for (int t = p; t <= qtB; t += 2) {
        const int  cur  = ((t - p) >> 1) & 1;
        const bool more = (t + 2 <= qtB);
        const bool actA = (t <= qtA);

        if (more) {
            size_t ko = (size_t)(t + 2) * 64 * DM;
            size_t vo = (size_t)(t + 2) * 64;
            kr0 = *(const uint4*)(kp + ko);
            kr1 = *(const uint4*)(kp + ko + (size_t)32 * DM);
            vr0 = *(const uint4*)(vp + vo);
            vr1 = *(const uint4*)(vp + vo + (size_t)32 * S_LEN);
        }

        short4v pbA[4], pbB[4];
        const bool diagA = (t == qtA);
        const bool diagB = (t == qtB);
        #pragma unroll
        for (int nt = 0; nt < 4; nt++) {
            floatx4 zB = (floatx4){0.f, 0.f, 0.f, 0.f};
            floatx4 zA = (floatx4){0.f, 0.f, 0.f, 0.f};
            #pragma unroll
            for (int ks = 0; ks < 2; ks++) {
                bf16x8 kf = *(const bf16x8*)(&Ks[cur][(nt * 16 + lcol) * FST + ks * 32 + lrow * 8]);
                zB = __builtin_amdgcn_mfma_f32_16x16x32_bf16(kf, qfB[ks], zB, 0, 0, 0);
                if (actA)
                    zA = __builtin_amdgcn_mfma_f32_16x16x32_bf16(kf, qfA[ks], zA, 0, 0, 0);
            }
            if (diagB) {
                #pragma unroll
                for (int r = 0; r < 4; r++) {
                    int kg = t * 64 + nt * 16 + lrow * 4 + r;
                    float pr = exp2f(zB[r] * sc2);
                    if (kg > q0B + lcol) pr = 0.f;
                    zB[r] = pr; lB += pr;
                }
            } else {
                #pragma unroll
                for (int r = 0; r < 4; r++) {
                    float pr = exp2f(zB[r] * sc2);
                    zB[r] = pr; lB += pr;
                }
            }
            bf16x4 pvB = { (bf16)zB[0], (bf16)zB[1], (bf16)zB[2], (bf16)zB[3] };
            pbB[nt] = __builtin_bit_cast(short4v, pvB);
            if (actA) {
                if (diagA) {
                    #pragma unroll
                    for (int r = 0; r < 4; r++) {
                        int kg = t * 64 + nt * 16 + lrow * 4 + r;
                        float pr = exp2f(zA[r] * sc2);
                        if (kg > q0A + lcol) pr = 0.f;
                        zA[r] = pr; lA += pr;
                    }
                } else {
                    #pragma unroll
                    for (int r = 0; r < 4; r++) {
                        float pr = exp2f(zA[r] * sc2);
                        zA[r] = pr; lA += pr;
                    }
                }
                bf16x4 pvA = { (bf16)zA[0], (bf16)zA[1], (bf16)zA[2], (bf16)zA[3] };
                pbA[nt] = __builtin_bit_cast(short4v, pvA);
            }
        }

        #pragma unroll
        for (int nt = 0; nt < 4; nt++)
            #pragma unroll
            for (int kt = 0; kt < 4; kt++) {
                bf16x4 va = *(const bf16x4*)(&Vs[cur][(nt * 16 + lcol) * FST + kt * 16 + lrow * 4]);
                short4v vas = __builtin_bit_cast(short4v, va);
                oaccB[nt] = __builtin_amdgcn_mfma_f32_16x16x16bf16_1k(vas, pbB[kt], oaccB[nt], 0, 0, 0);
                if (actA)
                    oaccA[nt] = __builtin_amdgcn_mfma_f32_16x16x16bf16_1k(vas, pbA[kt], oaccA[nt], 0, 0, 0);
            }

        if (more) {
            int nxt = cur ^ 1;
            *(uint4*)(&Ks[nxt][wof])            = kr0;
            *(uint4*)(&Ks[nxt][wof + 32 * FST]) = kr1;
            *(uint4*)(&Vs[nxt][wof])            = vr0;
            *(uint4*)(&Vs[nxt][wof + 32 * FST]) = vr1;
        }
        __syncthreads();
    }

    lA += __shfl_xor(lA, 16, 64);
    lA += __shfl_xor(lA, 32, 64);
    lB += __shfl_xor(lB, 16, 64);
    lB += __shfl_xor(lB, 32, 64);
    if (lrow == 0) {
        Lp[h * S_LEN + q0A + lcol] = lA;
        Lp[h * S_LEN + q0B + lcol] = lB;
    }
    #pragma unroll
    for (int nt = 0; nt < 4; nt++) {
        *(floatx4*)(&Op[(size_t)(q0A + lcol) * DM + h * HD + nt * 16 + lrow * 4]) = oaccA[nt];
        *(floatx4*)(&Op[(size_t)(q0B + lcol) * DM + h * HD + nt * 16 + lrow * 4]) = oaccB[nt];
    }
}

// ---------------------------------------------------------------------------
// Combine: Aw = (O0 + O1) / (l0 + l1), fp32 -> bf16.
// ---------------------------------------------------------------------------
__global__ void combine_kernel(const float* __restrict__ O0, const float* __restrict__ O1,
                               const float* __restrict__ L0, const float* __restrict__ L1,
                               bf16* __restrict__ Aw)
{
    int i4 = (blockIdx.x * 256 + threadIdx.x) * 4;   // 4M elems
    int q = i4 >> 10;
    int c = i4 & 1023;
    int h = c >> 6;
    float rl = 1.f / (L0[h * S_LEN + q] + L1[h * S_LEN + q]);
    float4 a = *(const float4*)(O0 + i4);
    float4 b = *(const float4*)(O1 + i4);
    bf16x4 o = { (bf16)((a.x + b.x) * rl), (bf16)((a.y + b.y) * rl),
                 (bf16)((a.z + b.z) * rl), (bf16)((a.w + b.w) * rl) };
    *(bf16x4*)(&Aw[i4]) = o;
}

// ---------------------------------------------------------------------------
// Output projection: out[M,N] = Aw[M,K] * wo[N,K]^T, 64x128 tiles (r10).
// ---------------------------------------------------------------------------
__launch_bounds__(256)
__global__ void gemm_out(const bf16* __restrict__ A, const bf16* __restrict__ B,
                         float* __restrict__ out)
{
    const int tid  = threadIdx.x;
    const int wave = tid >> 6;
    const int lane = tid & 63;
    const int wm   = (wave >> 1) * 32;
    const int wn   = (wave & 1) * 64;
    const int lrow = lane >> 4;
    const int lcol = lane & 15;

    const int m0 = blockIdx.y * 64;
    const int n0 = blockIdx.x * 128;

    __shared__ __align__(16) bf16 As[64 * 64];
    __shared__ __align__(16) bf16 Bs[128 * 64];

    floatx4 acc[2][4];
    #pragma unroll
    for (int i = 0; i < 2; i++)
        #pragma unroll
        for (int j = 0; j < 4; j++) acc[i][j] = (floatx4){0.f, 0.f, 0.f, 0.f};

    const bf16* ga0 = A + (size_t)(m0 + wave * 16 + (lane >> 3)) * GK + (lane & 7) * 8;
    const bf16* gb0 = B + (size_t)(n0 + wave * 32 + (lane >> 3)) * GK + (lane & 7) * 8;
    bf16* la = &As[(wave * 16) * 64];
    bf16* lb = &Bs[(wave * 32) * 64];

    for (int kt = 0; kt < GK; kt += 64) {
        #pragma unroll
        for (int i = 0; i < 2; i++)
            GLDS16(ga0 + kt + (size_t)i * 8 * GK, la + i * 8 * 64);
        #pragma unroll
        for (int i = 0; i < 4; i++)
            GLDS16(gb0 + kt + (size_t)i * 8 * GK, lb + i * 8 * 64);
        __syncthreads();
        #pragma unroll
        for (int ks = 0; ks < 2; ks++) {
            bf16x8 af[2], bfr[4];
            #pragma unroll
            for (int t = 0; t < 2; t++)
                af[t]  = *(const bf16x8*)(&As[(wm + t * 16 + lcol) * 64 + ks * 32 + lrow * 8]);
            #pragma unroll
            for (int t = 0; t < 4; t++)
                bfr[t] = *(const bf16x8*)(&Bs[(wn + t * 16 + lcol) * 64 + ks * 32 + lrow * 8]);
            #pragma unroll
            for (int mt = 0; mt < 2; mt++)
                #pragma unroll
                for (int nt = 0; nt < 4; nt++)
                    acc[mt][nt] = __builtin_amdgcn_mfma_f32_16x16x32_bf16(af[mt], bfr[nt], acc[mt][nt], 0, 0, 0);
        }
        __syncthreads();
    }

    #pragma unroll
    for (int mt = 0; mt < 2; mt++)
        #pragma unroll
        for (int nt = 0; nt < 4; nt++)
            #pragma unroll
            for (int r = 0; r < 4; r++) {
                int row = m0 + wm + mt * 16 + lrow * 4 + r;
                int col = n0 + wn + nt * 16 + lcol;
                out[(size_t)row * GN + col] = acc[mt][nt][r];
            }
}

// ---------------------------------------------------------------------------
extern "C" void kernel_launch(void* const* d_in, const int* in_sizes, int n_in,
                              void* d_out, int out_size, void* d_ws, size_t ws_size,
                              hipStream_t stream) {
    const float* x    = (const float*)d_in[0];
    const float* cosp = (const float*)d_in[1];
    const float* sinp = (const float*)d_in[2];
    const float* wq   = (const float*)d_in[4];
    const float* wk   = (const float*)d_in[5];
    const float* wv   = (const float*)d_in[6];
    const float* wo   = (const float*)d_in[7];
    float* out = (float*)d_out;

    const size_t SD = (size_t)S_LEN * DM;   // 4M elems
    const size_t DD = (size_t)DM * DM;      // 1M elems
    bf16* xb  = (bf16*)d_ws;                // 4M bf16
    bf16* wqb = xb + SD;
    bf16* wkb = wqb + DD;
    bf16* wvb = wkb + DD;
    bf16* wob = wvb + DD;
    bf16* Qw  = wob + DD;                   // 4M bf16 each
    bf16* Kw  = Qw + SD;
    bf16* VTw = Kw + SD;
    bf16* Aw  = VTw + SD;
    float* O0f = (float*)(Aw + SD);         // 4M fp32 each
    float* O1f = O0f + SD;
    float* L0f = O1f + SD;                  // 64K fp32 each
    float* L1f = L0f + (size_t)S_LEN * NH;

    // 1) fp32 -> bf16 (x + 4 weights)
    cvt_bf16<<<8192, 256, 0, stream>>>(x, wq, wk, wv, wo, xb);
    // 2) QKV projections + RoPE + V-transpose fused (64x128 tiles, 6 blk/CU)
    gemm_qkv<<<dim3(GN / 128, GM / 64, 3), 256, 0, stream>>>(
        xb, wqb, wkb, wvb, cosp, sinp, Qw, Kw, VTw);
    // 3) flash attention (parity-split partials)
    flash_attn<<<dim3(64, NH), 256, 0, stream>>>(Qw, Kw, VTw, O0f, O1f, L0f, L1f);
    // 4) combine partials -> bf16 Aw
    combine_kernel<<<S_LEN * DM / 1024, 256, 0, stream>>>(O0f, O1f, L0f, L1f, Aw);
    // 5) output projection
    gemm_out<<<dim3(GN / 128, GM / 64), 256, 0, stream>>>(Aw, wob, out);
}